// Round 15
// baseline (7205.843 us; speedup 1.0000x reference)
//
#include <hip/hip_runtime.h>

#define H 256
#define T_STEPS 128
#define B_BATCH 256
#define XGRP2 68      // padded 64-float segment stride: 4 segments 4 banks apart

#define LOG2E 1.4426950408889634f

union CVH { unsigned int u; _Float16 h[2]; };

__device__ __forceinline__ float fexp2_(float x) {
#if __has_builtin(__builtin_amdgcn_exp2f)
    return __builtin_amdgcn_exp2f(x);
#else
    return exp2f(x);
#endif
}
__device__ __forceinline__ float frcp_(float x) {
#if __has_builtin(__builtin_amdgcn_rcpf)
    float r = __builtin_amdgcn_rcpf(x);
    return r * (2.0f - x * r);          // 1 Newton step -> ~0.5 ulp
#else
    return 1.0f / x;
#endif
}
// fast tanh/sigmoid: measured bf16-exact vs np ref (rounds 8-14)
__device__ __forceinline__ float tanhf_(float x) {
    float xc = fminf(fmaxf(x, -16.f), 16.f);
    float t  = fexp2_(xc * (2.f * LOG2E));
    return (t - 1.f) * frcp_(t + 1.f);
}
__device__ __forceinline__ float sigmoidf_(float x) {
    float xc = fminf(fmaxf(x, -30.f), 30.f);
    return frcp_(1.f + fexp2_(-xc * LOG2E));
}

// ---------------- prep kernels (tiny, once per launch; cold path) ----------------

__global__ void prep_weff(const float* __restrict__ W1, const float* __restrict__ W2,
                          const float* __restrict__ b1, const float* __restrict__ b2,
                          float* __restrict__ Weff, float* __restrict__ beff) {
    int i = blockIdx.x, j = threadIdx.x;
    const float* w2row = W2 + j * H;
    float acc = 0.f;
    for (int d = 0; d < H; ++d) acc += W1[d * H + i] * w2row[d];
    Weff[i * H + j] = acc;
    if (i == 0) {
        float bacc = b2[j];
        for (int d = 0; d < H; ++d) bacc += b1[d] * w2row[d];
        beff[j] = bacc;
    }
}

// pack Weff row, col-pair {2jp,2jp+1} into one dword of 2 f16 (RNE)
__global__ void prep_weffh16(const float* __restrict__ Weff, unsigned int* __restrict__ W16) {
    int idx = blockIdx.x * 1024 + threadIdx.x;  // 32768
    int row = idx >> 7, jp = idx & 127;
    CVH cv;
    cv.h[0] = (_Float16)Weff[row * H + 2 * jp];
    cv.h[1] = (_Float16)Weff[row * H + 2 * jp + 1];
    W16[idx] = cv.u;
}

__global__ void prep_whht(const float* __restrict__ Whh, float* __restrict__ WhhT) {
    int idx = blockIdx.x * blockDim.x + threadIdx.x;  // 196608
    int i = idx / 768;
    int r = idx - i * 768;
    WhhT[idx] = Whh[r * H + i];
}

// pack ALL rows: dword i2*768+r = f16pair(WhhT[2i2][r], WhhT[2i2+1][r])
__global__ void prep_whh16f(const float* __restrict__ WhhT, unsigned int* __restrict__ W16) {
    int idx = blockIdx.x * blockDim.x + threadIdx.x;  // 98304
    int i2 = idx / 768;
    int r  = idx - i2 * 768;
    CVH cv;
    cv.h[0] = (_Float16)WhhT[(2 * i2) * 768 + r];
    cv.h[1] = (_Float16)WhhT[(2 * i2 + 1) * 768 + r];
    W16[idx] = cv.u;
}

__global__ void prep_wo(const float* __restrict__ Wo1, const float* __restrict__ Wo2,
                        const float* __restrict__ bo1, const float* __restrict__ bo2,
                        float* __restrict__ wo, float* __restrict__ bo) {
    int i = threadIdx.x;
    float acc = 0.f;
    for (int d = 0; d < H; ++d) acc += Wo1[d * H + i] * Wo2[d];
    wo[i] = acc;
    float p = bo1[i] * Wo2[i];
    __shared__ float red[4];
    for (int off = 32; off > 0; off >>= 1) p += __shfl_down(p, off);
    if ((i & 63) == 0) red[i >> 6] = p;
    __syncthreads();
    if (i == 0) bo[0] = red[0] + red[1] + red[2] + red[3] + bo2[0];
}

// ---------------- main scan: 512-thread block per row, 2 blocks/CU ----------------
// STRUCTURAL change vs rounds 7-14 (all plateaued ~2100us at 48% VALUBusy,
// one 16-wave lockstep block/CU): 512 threads/block, 8 waves, LDS ~10KB ->
// TWO independent blocks co-resident per CU.  When one block drains a
// barrier or sits in an LDS/tanh latency chain, the other issues -- the
// measured ~85% phase-latency overhead becomes overlappable.
// tid = jp*4 + e: jp owns column pair {2jp,2jp+1}; e in [0,4) = 64-row
// K-slice; c=e&1 -> finalized column jc.  64 f16-packed Weff dwords pinned
// (f16 weights proven output-exact, r13/r14).  EVAL: 16 broadcast b128
// reads (4 segments, 4 banks apart), 128 mixed FMA, 2-shuffle reduce.
// gh: ALL 256 rows f16-streamed from L2 (consecutive lanes -> consecutive
// dwords; r13 proved bytes off-critical-path), two passes: A = outputs
// 0-511, B = outputs 512-767 (threads 0-255) || out-head (threads 256-511).
// All state/accum f32 (f16 STATE diverges, round 2).

__global__ __attribute__((amdgpu_flat_work_group_size(512, 512),
                          amdgpu_waves_per_eu(4, 4)))
void ode_rnn_main(
    const float* __restrict__ b_in, const float* __restrict__ m_in,
    const float* __restrict__ trm_in, const float* __restrict__ tem_in,
    const float* __restrict__ h0,
    const unsigned int* __restrict__ WeffH16, const float* __restrict__ beff,
    const unsigned int* __restrict__ Whh16f,
    const float* __restrict__ W_ih, const float* __restrict__ b_ih,
    const float* __restrict__ b_hh,
    const float* __restrict__ wo, const float* __restrict__ bo_p,
    float* __restrict__ out)
{
    const int tid = threadIdx.x;
    const int bb  = blockIdx.x;
    const int jp  = tid >> 2;     // column pair 0..127
    const int e   = tid & 3;      // K-slice quarter (64 rows)
    const int c   = e & 1;
    const int jc  = 2 * jp + c;

    __shared__ __align__(16) float xsb[2][4 * XGRP2];    // 2176 B
    __shared__ __align__(16) float xsf[H];               // hp (linear)
    __shared__ float gh_lds[768];
    __shared__ float red[4];
    __shared__ float times_s[T_STEPS];
    __shared__ float bv_s[T_STEPS], trm_s[T_STEPS], tem_s[T_STEPS], m_s[T_STEPS];

    // Weff tile: rows 64e..64e+63 x cols {2jp,2jp+1}, f16-packed, pinned
    unsigned int wregh[64];
    #pragma unroll
    for (int il = 0; il < 64; ++il)
        wregh[il] = WeffH16[(64 * e + il) * 128 + jp];
    #pragma unroll
    for (int il = 0; il < 64; ++il)
        asm volatile("" : "+v"(wregh[il]));

    if (tid < T_STEPS) {
        times_s[tid] = b_in[2 * tid];   // times identical across batch
        int bt = bb * T_STEPS + tid;
        bv_s[tid]  = b_in[2 * bt + 1];
        trm_s[tid] = trm_in[bt];
        tem_s[tid] = tem_in[bt];
        m_s[tid]   = m_in[bt];
    }

    float h = h0[bb * H + jc];
    const float be   = beff[jc];
    const float bihr = b_ih[jc], bihz = b_ih[H + jc], bihn = b_ih[2 * H + jc];
    const float bhhr = b_hh[jc], bhhz = b_hh[H + jc], bhhn = b_hh[2 * H + jc];
    const float wihr = W_ih[jc], wihz = W_ih[H + jc], wihn = W_ih[2 * H + jc];
    const float bo   = bo_p[0];
    const float wo_t = (tid >= 256) ? wo[tid - 256] : 0.f;

    // publish slot (valid when e < 2: then jc == 2jp+e)
    const int pubpos = (jc >> 6) * XGRP2 + (jc & 63);

    if (e < 2) xsb[0][pubpos] = h;     // initial publish (step 0 reads buf 0)
    __syncthreads();

    // eval: 16 broadcast b128 reads (segment e), 128 mixed FMA (2 cols),
    // 2-shuffle folded reduce over the 4 e-lanes, fast tanh
    #define EVAL(KOUT_) do {                                       \
        const float* xp_ = &xsb[cur][e * XGRP2];                   \
        float a0_ = 0.f, a1_ = 0.f, b0_ = 0.f, b1_ = 0.f;          \
        _Pragma("unroll")                                          \
        for (int g_ = 0; g_ < 16; ++g_) {                          \
            float4 x_ = ((const float4*)xp_)[g_];                  \
            CVH w0_, w1_, w2_, w3_;                                \
            w0_.u = wregh[4 * g_ + 0];                             \
            w1_.u = wregh[4 * g_ + 1];                             \
            w2_.u = wregh[4 * g_ + 2];                             \
            w3_.u = wregh[4 * g_ + 3];                             \
            a0_ = fmaf((float)w0_.h[0], x_.x, a0_);                \
            b0_ = fmaf((float)w0_.h[1], x_.x, b0_);                \
            a1_ = fmaf((float)w1_.h[0], x_.y, a1_);                \
            b1_ = fmaf((float)w1_.h[1], x_.y, b1_);                \
            a0_ = fmaf((float)w2_.h[0], x_.z, a0_);                \
            b0_ = fmaf((float)w2_.h[1], x_.z, b0_);                \
            a1_ = fmaf((float)w3_.h[0], x_.w, a1_);                \
            b1_ = fmaf((float)w3_.h[1], x_.w, b1_);                \
        }                                                          \
        float s0_ = a0_ + a1_, s1_ = b0_ + b1_;                    \
        float v_ = (c == 0) ? s0_ : s1_;                           \
        float u_ = (c == 0) ? s1_ : s0_;                           \
        v_ += __shfl_xor(u_, 1);                                   \
        v_ += __shfl_xor(v_, 2);                                   \
        KOUT_ = tanhf_(be + v_);                                   \
    } while (0)

    // publish next matvec arg (lanes e<2, one b32 each); barrier; flip
    #define PUBLISH(V_) do {                                       \
        if (e < 2) xsb[cur ^ 1][pubpos] = (V_);                    \
        __syncthreads();                                           \
        cur ^= 1;                                                  \
    } while (0)

    // one full-K f16 gh walk for output index O_ into accumulator pair sums
    #define GH_WALK(O_, DST_) do {                                 \
        const unsigned int* wp_ = Whh16f + (O_);                   \
        float c0_ = 0.f, c1_ = 0.f, c2_ = 0.f, c3_ = 0.f;          \
        _Pragma("unroll 16")                                       \
        for (int ii_ = 0; ii_ < 128; ii_ += 2) {                   \
            float4 xv_ = *(const float4*)(xsf + 2 * ii_);          \
            CVH ca_, cb_;                                          \
            ca_.u = wp_[ii_ * 768];                                \
            cb_.u = wp_[(ii_ + 1) * 768];                          \
            c0_ = fmaf(xv_.x, (float)ca_.h[0], c0_);               \
            c1_ = fmaf(xv_.y, (float)ca_.h[1], c1_);               \
            c2_ = fmaf(xv_.z, (float)cb_.h[0], c2_);               \
            c3_ = fmaf(xv_.w, (float)cb_.h[1], c3_);               \
        }                                                          \
        DST_ = (c0_ + c1_) + (c2_ + c3_);                          \
    } while (0)

    float tprev = 0.f;
    #pragma unroll 1
    for (int t = 0; t < T_STEPS; ++t) {
        float t1 = times_s[t];
        float dt = (t1 - tprev) * 0.5f;   // per-substep dt (N_SUB=2)
        tprev = t1;

        int cur = 0;
        float k1, k2, k3, k4;
        #pragma unroll 1
        for (int s = 0; s < 2; ++s) {
            EVAL(k1); PUBLISH(fmaf(0.5f * dt, k1, h));
            EVAL(k2); PUBLISH(fmaf(0.5f * dt, k2, h));
            EVAL(k3); PUBLISH(fmaf(dt, k3, h));
            EVAL(k4);
            h = fmaf(dt * (1.f / 6.f), k1 + 2.f * (k2 + k3) + k4, h);
            if (s == 0) PUBLISH(h);   // substep-2 k1 reads h
        }

        // stage hp (linear) for gh + out head
        if (e < 2) xsf[jc] = h;
        __syncthreads();

        // gh pass A: outputs 0..511 (r and z gates), one per thread
        {
            float ga;
            GH_WALK(tid, ga);
            gh_lds[tid] = ga;
        }
        // gh pass B: outputs 512..767 (n gate) on threads 0..255
        // || out-head dot on threads 256..511
        if (tid < 256) {
            float gb;
            GH_WALK(512 + tid, gb);
            gh_lds[512 + tid] = gb;
        } else {
            float p = xsf[tid - 256] * wo_t;
            #pragma unroll
            for (int off = 32; off > 0; off >>= 1) p += __shfl_down(p, off);
            if ((tid & 63) == 0) red[(tid - 256) >> 6] = p;
        }
        __syncthreads();

        // gates: ALL threads compute for their jc (replicated, bit-identical)
        {
            float outv = tanhf_(red[0] + red[1] + red[2] + red[3] + bo);
            float bv = bv_s[t], trm = trm_s[t], tem = tem_s[t], mv = m_s[t];
            float ghr = gh_lds[jc] + bhhr;
            float ghz = gh_lds[256 + jc] + bhhz;
            float ghn = gh_lds[512 + jc] + bhhn;
            float x1v = bv * trm, x2v = outv * tem;

            float r1 = sigmoidf_(fmaf(x1v, wihr, bihr) + ghr);
            float z1 = sigmoidf_(fmaf(x1v, wihz, bihz) + ghz);
            float n1 = tanhf_(fmaf(x1v, wihn, bihn) + r1 * ghn);
            float h1 = (1.f - z1) * n1 + z1 * h;

            float r2 = sigmoidf_(fmaf(x2v, wihr, bihr) + ghr);
            float z2 = sigmoidf_(fmaf(x2v, wihz, bihz) + ghz);
            float n2 = tanhf_(fmaf(x2v, wihn, bihn) + r2 * ghn);
            float h2 = (1.f - z2) * n2 + z2 * h;

            if (tid == 0) out[bb * T_STEPS + t] = outv;
            h = trm * h1 + tem * h2 + (1.f - mv) * h;
        }

        // publish h_new for next step's first eval (reads buf 0)
        if (e < 2) xsb[0][pubpos] = h;
        __syncthreads();
    }
    #undef EVAL
    #undef PUBLISH
    #undef GH_WALK
}

// ---------------- launcher ----------------

extern "C" void kernel_launch(void* const* d_in, const int* in_sizes, int n_in,
                              void* d_out, int out_size, void* d_ws, size_t ws_size,
                              hipStream_t stream) {
    const float* b_in = (const float*)d_in[0];
    const float* m_in = (const float*)d_in[1];
    const float* trm  = (const float*)d_in[2];
    const float* tem  = (const float*)d_in[3];
    const float* h0   = (const float*)d_in[4];
    const float* W1   = (const float*)d_in[5];
    const float* b1   = (const float*)d_in[6];
    const float* W2   = (const float*)d_in[7];
    const float* b2   = (const float*)d_in[8];
    const float* W_ih = (const float*)d_in[9];
    const float* W_hh = (const float*)d_in[10];
    const float* b_ih = (const float*)d_in[11];
    const float* b_hh = (const float*)d_in[12];
    const float* Wo1  = (const float*)d_in[13];
    const float* bo1  = (const float*)d_in[14];
    const float* Wo2  = (const float*)d_in[15];
    const float* bo2  = (const float*)d_in[16];

    float* ws = (float*)d_ws;
    float*        Weff    = ws;                             // 65536
    float*        beff    = Weff + 65536;                   // 256
    float*        WhhT    = beff + 256;                     // 196608
    float*        wo      = WhhT + 196608;                  // 256
    float*        bo      = wo + 256;                       // 1
    unsigned int* Whh16f  = (unsigned int*)(bo + 1);        // 98304 dwords
    unsigned int* WeffH16 = Whh16f + 98304;                 // 32768 dwords

    prep_weff<<<256, 256, 0, stream>>>(W1, W2, b1, b2, Weff, beff);
    prep_weffh16<<<32, 1024, 0, stream>>>(Weff, WeffH16);
    prep_whht<<<192, 1024, 0, stream>>>(W_hh, WhhT);
    prep_whh16f<<<96, 1024, 0, stream>>>(WhhT, Whh16f);
    prep_wo<<<1, 256, 0, stream>>>(Wo1, Wo2, bo1, bo2, wo, bo);

    ode_rnn_main<<<B_BATCH, 512, 0, stream>>>(b_in, m_in, trm, tem, h0,
                                              WeffH16, beff, Whh16f,
                                              W_ih, b_ih, b_hh, wo, bo,
                                              (float*)d_out);
}

// Round 16
// 2019.912 us; speedup vs baseline: 3.5674x; 3.5674x over previous
//
#include <hip/hip_runtime.h>

#define H 256
#define T_STEPS 128
#define B_BATCH 256
#define I_LDS 48      // WhhT rows [0,48) persistent in LDS (48*768*4B = 147456 B)
#define XGRP 36       // words per 32-float xs segment: 8 segments hit disjoint bank-quads

#define LOG2E 1.4426950408889634f

__device__ __forceinline__ float fexp2_(float x) {
#if __has_builtin(__builtin_amdgcn_exp2f)
    return __builtin_amdgcn_exp2f(x);
#else
    return exp2f(x);
#endif
}
__device__ __forceinline__ float frcp_(float x) {
#if __has_builtin(__builtin_amdgcn_rcpf)
    float r = __builtin_amdgcn_rcpf(x);
    return r * (2.0f - x * r);          // 1 Newton step -> ~0.5 ulp
#else
    return 1.0f / x;
#endif
}
// fast tanh: (e^{2x}-1)/(e^{2x}+1); measured bf16-exact vs np ref (rounds 8-14)
__device__ __forceinline__ float tanhf_(float x) {
    float xc = fminf(fmaxf(x, -16.f), 16.f);
    float t  = fexp2_(xc * (2.f * LOG2E));
    return (t - 1.f) * frcp_(t + 1.f);
}
__device__ __forceinline__ float sigmoidf_(float x) {
    float xc = fminf(fmaxf(x, -30.f), 30.f);
    return frcp_(1.f + fexp2_(-xc * LOG2E));
}

// ---------------- prep kernels (tiny, once per launch; cold path) ----------------

__global__ void prep_weff(const float* __restrict__ W1, const float* __restrict__ W2,
                          const float* __restrict__ b1, const float* __restrict__ b2,
                          float* __restrict__ Weff, float* __restrict__ beff) {
    int i = blockIdx.x, j = threadIdx.x;
    const float* w2row = W2 + j * H;
    float acc = 0.f;
    for (int d = 0; d < H; ++d) acc += W1[d * H + i] * w2row[d];
    Weff[i * H + j] = acc;
    if (i == 0) {
        float bacc = b2[j];
        for (int d = 0; d < H; ++d) bacc += b1[d] * w2row[d];
        beff[j] = bacc;
    }
}

__global__ void prep_whht(const float* __restrict__ Whh, float* __restrict__ WhhT) {
    int idx = blockIdx.x * blockDim.x + threadIdx.x;  // 196608 total
    int i = idx / 768;
    int r = idx - i * 768;
    WhhT[idx] = Whh[r * H + i];
}

__global__ void prep_wo(const float* __restrict__ Wo1, const float* __restrict__ Wo2,
                        const float* __restrict__ bo1, const float* __restrict__ bo2,
                        float* __restrict__ wo, float* __restrict__ bo) {
    int i = threadIdx.x;
    float acc = 0.f;
    for (int d = 0; d < H; ++d) acc += Wo1[d * H + i] * Wo2[d];
    wo[i] = acc;
    float p = bo1[i] * Wo2[i];
    __shared__ float red[4];
    for (int off = 32; off > 0; off >>= 1) p += __shfl_down(p, off);
    if ((i & 63) == 0) red[i >> 6] = p;
    __syncthreads();
    if (i == 0) bo[0] = red[0] + red[1] + red[2] + red[3] + bo2[0];
}

// ---------------- main scan: 1 block (1024 thr) per batch row ----------------
// FINAL: round-10 kernel verbatim -- the measured best (2028.5us, absmax
// 4.88e-4 = 1 output ulp).  Structure: tid = jp*8 + e; jp owns column pair
// {2jp,2jp+1}; e = K-slice eighth; c=e&1 -> finalized column jc.  32 float2
// Weff weights pinned in regs (remat-proof).  EVAL: 8 broadcast b128 LDS
// reads (conflict-free), 64 FMA, folded 3-shuffle reduce, fast tanh
// (v_exp/v_rcp, proven bf16-exact).  gh: scalar column walk (consecutive
// tids -> consecutive banks/addresses), rows [0,48) from LDS, rest from L2.
// Closed branches (measured): f16 state (diverges, r2); gh restructures
// (r8 LDS-conflict, r9 quad-L2, r12 row-walk -- all stall-bound); Whh in
// registers (impossible: 1MB weights vs 512KB RF, r11); EVAL-traffic and
// gh-byte cuts (off critical path, r7/r13); 2 blocks/CU (spills, r15).
// Remaining time = latency floor of the 128-step x 12-phase serial chain.

__global__ __attribute__((amdgpu_flat_work_group_size(1024, 1024),
                          amdgpu_waves_per_eu(4, 4)))
void ode_rnn_main(
    const float* __restrict__ b_in, const float* __restrict__ m_in,
    const float* __restrict__ trm_in, const float* __restrict__ tem_in,
    const float* __restrict__ h0,
    const float* __restrict__ Weff, const float* __restrict__ beff,
    const float* __restrict__ WhhT,
    const float* __restrict__ W_ih, const float* __restrict__ b_ih,
    const float* __restrict__ b_hh,
    const float* __restrict__ wo, const float* __restrict__ bo_p,
    float* __restrict__ out)
{
    const int tid = threadIdx.x;
    const int bb  = blockIdx.x;
    const int jp  = tid >> 3;     // column pair 0..127
    const int e   = tid & 7;      // K-slice eighth
    const int c   = e & 1;
    const int jc  = 2 * jp + c;

    __shared__ float whh_lds[I_LDS * 768];               // 147456 B
    __shared__ __align__(16) float xsb[2][8 * XGRP];     // 2304 B
    __shared__ __align__(16) float xsf[H];               // hp (linear)
    __shared__ float gh_lds[768];
    __shared__ float red[4];
    __shared__ float times_s[T_STEPS];
    __shared__ float bv_s[T_STEPS], trm_s[T_STEPS], tem_s[T_STEPS], m_s[T_STEPS];

    // Weff tile: rows 32e..32e+31 x cols {2jp, 2jp+1}, pinned in regs
    float2 wregv[32];
    #pragma unroll
    for (int il = 0; il < 32; ++il)
        wregv[il] = *(const float2*)&Weff[(32 * e + il) * H + 2 * jp];
    #pragma unroll
    for (int il = 0; il < 32; ++il)
        asm volatile("" : "+v"(wregv[il].x), "+v"(wregv[il].y));

    // stage WhhT rows [0,I_LDS) + per-step scalars
    for (int k = tid; k < I_LDS * 768; k += 1024) whh_lds[k] = WhhT[k];
    if (tid < T_STEPS) {
        times_s[tid] = b_in[2 * tid];   // times identical across batch
        int bt = bb * T_STEPS + tid;
        bv_s[tid]  = b_in[2 * bt + 1];
        trm_s[tid] = trm_in[bt];
        tem_s[tid] = tem_in[bt];
        m_s[tid]   = m_in[bt];
    }

    float h = h0[bb * H + jc];
    const float be   = beff[jc];
    const float bihr = b_ih[jc], bihz = b_ih[H + jc], bihn = b_ih[2 * H + jc];
    const float bhhr = b_hh[jc], bhhz = b_hh[H + jc], bhhn = b_hh[2 * H + jc];
    const float wihr = W_ih[jc], wihz = W_ih[H + jc], wihn = W_ih[2 * H + jc];
    const float bo   = bo_p[0];
    const float wo_t = (tid >= 768) ? wo[tid - 768] : 0.f;

    // publish slot for this thread's column (valid when e < 2: then jc == 2jp+e)
    const int pubpos = (jc >> 5) * XGRP + (jc & 31);

    if (e < 2) xsb[0][pubpos] = h;     // initial publish (step 0 reads buf 0)
    __syncthreads();

    // eval: 8 broadcast b128 reads, 64 FMA (2 cols), folded 3-shuffle reduce, tanh
    #define EVAL(KOUT_) do {                                       \
        const float* xp_ = &xsb[cur][e * XGRP];                    \
        float a0_ = 0.f, a1_ = 0.f, b0_ = 0.f, b1_ = 0.f;          \
        _Pragma("unroll")                                          \
        for (int g_ = 0; g_ < 8; ++g_) {                           \
            float4 x_ = ((const float4*)xp_)[g_];                  \
            a0_ = fmaf(x_.x, wregv[4 * g_ + 0].x, a0_);            \
            b0_ = fmaf(x_.x, wregv[4 * g_ + 0].y, b0_);            \
            a1_ = fmaf(x_.y, wregv[4 * g_ + 1].x, a1_);            \
            b1_ = fmaf(x_.y, wregv[4 * g_ + 1].y, b1_);            \
            a0_ = fmaf(x_.z, wregv[4 * g_ + 2].x, a0_);            \
            b0_ = fmaf(x_.z, wregv[4 * g_ + 2].y, b0_);            \
            a1_ = fmaf(x_.w, wregv[4 * g_ + 3].x, a1_);            \
            b1_ = fmaf(x_.w, wregv[4 * g_ + 3].y, b1_);            \
        }                                                          \
        float s0_ = a0_ + a1_, s1_ = b0_ + b1_;                    \
        float v_ = (c == 0) ? s0_ : s1_;                           \
        float u_ = (c == 0) ? s1_ : s0_;                           \
        v_ += __shfl_xor(u_, 1);                                   \
        v_ += __shfl_xor(v_, 2);                                   \
        v_ += __shfl_xor(v_, 4);                                   \
        KOUT_ = tanhf_(be + v_);                                   \
    } while (0)

    // publish next matvec arg (lanes e<2, one b32 each); barrier; flip
    #define PUBLISH(V_) do {                                       \
        if (e < 2) xsb[cur ^ 1][pubpos] = (V_);                    \
        __syncthreads();                                           \
        cur ^= 1;                                                  \
    } while (0)

    float tprev = 0.f;
    #pragma unroll 1
    for (int t = 0; t < T_STEPS; ++t) {
        float t1 = times_s[t];
        float dt = (t1 - tprev) * 0.5f;   // per-substep dt (N_SUB=2)
        tprev = t1;

        int cur = 0;
        float k1, k2, k3, k4;
        #pragma unroll 1
        for (int s = 0; s < 2; ++s) {
            EVAL(k1); PUBLISH(fmaf(0.5f * dt, k1, h));
            EVAL(k2); PUBLISH(fmaf(0.5f * dt, k2, h));
            EVAL(k3); PUBLISH(fmaf(dt, k3, h));
            EVAL(k4);
            h = fmaf(dt * (1.f / 6.f), k1 + 2.f * (k2 + k3) + k4, h);
            if (s == 0) PUBLISH(h);   // substep-2 k1 reads h
        }

        // stage hp (linear) for gh + out head
        if (e < 2) xsf[jc] = h;
        __syncthreads();

        // gh = hp @ W_hh^T: rows [0,I_LDS) from LDS, rest streamed from L2.
        // (scalar walk: consecutive tids -> consecutive banks, conflict-free;
        //  one 256B transaction per wave-load; 208 independent loads pipeline)
        // || out-head dot (waves 12..15)
        if (tid < 768) {
            float g0 = 0.f, g1 = 0.f, g2 = 0.f, g3 = 0.f;
            const float* wl = whh_lds + tid;
            #pragma unroll 4
            for (int i = 0; i < I_LDS; i += 4) {
                float4 xv = *(const float4*)(xsf + i);
                g0 = fmaf(xv.x, wl[(i + 0) * 768], g0);
                g1 = fmaf(xv.y, wl[(i + 1) * 768], g1);
                g2 = fmaf(xv.z, wl[(i + 2) * 768], g2);
                g3 = fmaf(xv.w, wl[(i + 3) * 768], g3);
            }
            const float* wr = WhhT + I_LDS * 768 + tid;
            #pragma unroll 8
            for (int i = 0; i < H - I_LDS; i += 4) {
                float4 xv = *(const float4*)(xsf + I_LDS + i);
                g0 = fmaf(xv.x, wr[(i + 0) * 768], g0);
                g1 = fmaf(xv.y, wr[(i + 1) * 768], g1);
                g2 = fmaf(xv.z, wr[(i + 2) * 768], g2);
                g3 = fmaf(xv.w, wr[(i + 3) * 768], g3);
            }
            gh_lds[tid] = (g0 + g1) + (g2 + g3);
        } else {
            float p = xsf[tid - 768] * wo_t;
            #pragma unroll
            for (int off = 32; off > 0; off >>= 1) p += __shfl_down(p, off);
            if ((tid & 63) == 0) red[(tid - 768) >> 6] = p;
        }
        __syncthreads();

        // gates: ALL threads compute for their jc (replicated, bit-identical)
        {
            float outv = tanhf_(red[0] + red[1] + red[2] + red[3] + bo);
            float bv = bv_s[t], trm = trm_s[t], tem = tem_s[t], mv = m_s[t];
            float ghr = gh_lds[jc] + bhhr;
            float ghz = gh_lds[256 + jc] + bhhz;
            float ghn = gh_lds[512 + jc] + bhhn;
            float x1v = bv * trm, x2v = outv * tem;

            float r1 = sigmoidf_(fmaf(x1v, wihr, bihr) + ghr);
            float z1 = sigmoidf_(fmaf(x1v, wihz, bihz) + ghz);
            float n1 = tanhf_(fmaf(x1v, wihn, bihn) + r1 * ghn);
            float h1 = (1.f - z1) * n1 + z1 * h;

            float r2 = sigmoidf_(fmaf(x2v, wihr, bihr) + ghr);
            float z2 = sigmoidf_(fmaf(x2v, wihz, bihz) + ghz);
            float n2 = tanhf_(fmaf(x2v, wihn, bihn) + r2 * ghn);
            float h2 = (1.f - z2) * n2 + z2 * h;

            if (tid == 0) out[bb * T_STEPS + t] = outv;
            h = trm * h1 + tem * h2 + (1.f - mv) * h;
        }

        // publish h_new for next step's first eval (reads buf 0)
        if (e < 2) xsb[0][pubpos] = h;
        __syncthreads();
    }
    #undef EVAL
    #undef PUBLISH
}

// ---------------- launcher ----------------

extern "C" void kernel_launch(void* const* d_in, const int* in_sizes, int n_in,
                              void* d_out, int out_size, void* d_ws, size_t ws_size,
                              hipStream_t stream) {
    const float* b_in = (const float*)d_in[0];
    const float* m_in = (const float*)d_in[1];
    const float* trm  = (const float*)d_in[2];
    const float* tem  = (const float*)d_in[3];
    const float* h0   = (const float*)d_in[4];
    const float* W1   = (const float*)d_in[5];
    const float* b1   = (const float*)d_in[6];
    const float* W2   = (const float*)d_in[7];
    const float* b2   = (const float*)d_in[8];
    const float* W_ih = (const float*)d_in[9];
    const float* W_hh = (const float*)d_in[10];
    const float* b_ih = (const float*)d_in[11];
    const float* b_hh = (const float*)d_in[12];
    const float* Wo1  = (const float*)d_in[13];
    const float* bo1  = (const float*)d_in[14];
    const float* Wo2  = (const float*)d_in[15];
    const float* bo2  = (const float*)d_in[16];

    float* ws   = (float*)d_ws;
    float* Weff = ws;             // 65536
    float* beff = Weff + 65536;   // 256
    float* WhhT = beff + 256;     // 196608
    float* wo   = WhhT + 196608;  // 256
    float* bo   = wo + 256;       // 1

    prep_weff<<<256, 256, 0, stream>>>(W1, W2, b1, b2, Weff, beff);
    prep_whht<<<192, 1024, 0, stream>>>(W_hh, WhhT);
    prep_wo<<<1, 256, 0, stream>>>(Wo1, Wo2, bo1, bo2, wo, bo);

    ode_rnn_main<<<B_BATCH, 1024, 0, stream>>>(b_in, m_in, trm, tem, h0,
                                               Weff, beff, WhhT,
                                               W_ih, b_ih, b_hh, wo, bo,
                                               (float*)d_out);
}